// Round 2
// baseline (397.876 us; speedup 1.0000x reference)
//
#include <hip/hip_runtime.h>
#include <cstdint>

// Problem constants (from reference)
#define BB 32
#define TV 8192
#define KK 64
#define TS 128
#define MARGIN_F 0.1f
#define LAMBDA_F 0.5f

static constexpr int KSTR = BB * TV;  // pred_intervened stride per k (floats)

// Workspace layout (floats):
//   gsa[KK*BB]  : sum(eff * aligned)   per (k,b)
//   gsv[KK*BB]  : sum(eff * valid)     per (k,b)
//   gca[KK*BB]  : count(aligned)       per (k,b)  (exact in float, <= 8192)
//   gcv[BB]     : count(valid)         per b
// en = (gsv - gsa) / (gcv - gca); cn = gcv - gca (aligned subset of valid).

// ---------------------------------------------------------------------------
// Fused kernel: each wave owns 64 consecutive rows r = b*TV + t.
// Phase A: coalesced int4 stream of gt_mask + ballot-transpose -> per-row
//          64-bit word A (bit k = gt[b,t,idx[k]]>0 && valid[b,t]) in LDS.
//          (Bit logic identical to the R1 pack_kernel that verified absmax 0.)
// Phase B: k-loop; coalesced pred_intervened reads; per-k wave reduction of
//          (sum eff*aligned, sum eff*valid); counts via ballot+popcount;
//          one atomicAdd triple per (wave,k).
// ---------------------------------------------------------------------------
__global__ __launch_bounds__(256) void fused_kernel(
    const float* __restrict__ po, const float* __restrict__ pi,
    const int* __restrict__ idx, const int* __restrict__ gt,
    const int* __restrict__ mv,
    float* __restrict__ gsa, float* __restrict__ gsv,
    float* __restrict__ gca, float* __restrict__ gcv) {
  const int lane = threadIdx.x & 63;
  const int w = threadIdx.x >> 6;
  const int wave = blockIdx.x * 4 + w;
  const int r0 = wave * 64;            // 4096 waves * 64 rows = B*TV
  const int b = r0 >> 13;              // TV = 8192
  const int c = idx[lane];             // lane extracts column for k = lane
  const int csel = c & 3, csh = c >> 2;

  __shared__ unsigned long long lA[256];          // 64 words per wave
  unsigned long long* A = lA + w * 64;

  // validity bits for these 64 rows (all same b: TV % 64 == 0)
  const unsigned long long V = __ballot(mv[r0 + lane] != 0);

  // --- Phase A: pack gt columns idx[0..63] for rows r0..r0+63 ---
  const int4* rowp = (const int4*)(gt + (size_t)r0 * TS);
#pragma unroll 2
  for (int ch = 0; ch < 32; ++ch) {
    int4 v = rowp[ch * 64 + lane];     // 1024 B / wave-load = 2 full rows
    unsigned long long b0 = __ballot(v.x > 0);
    unsigned long long b1 = __ballot(v.y > 0);
    unsigned long long b2 = __ballot(v.z > 0);
    unsigned long long b3 = __ballot(v.w > 0);
    unsigned long long sel = (csel == 0) ? b0 : (csel == 1) ? b1 : (csel == 2) ? b2 : b3;
    int raw0 = (int)((sel >> csh) & 1ull);          // row r0+2ch, col c
    int raw1 = (int)((sel >> (32 + csh)) & 1ull);   // row r0+2ch+1, col c
    const int rlo = 2 * ch, rhi = 2 * ch + 1;
    const int v0 = (int)((V >> rlo) & 1ull);
    const int v1 = (int)((V >> rhi) & 1ull);
    unsigned long long A0 = __ballot(v0 & raw0);    // bit k = aligned(k, rlo)
    unsigned long long A1 = __ballot(v1 & raw1);
    if (lane == 0) { A[rlo] = A0; A[rhi] = A1; }
  }
  __syncthreads();

  // --- Phase B ---
  const unsigned long long Am = A[lane];            // my row's aligned bits
  const int vb = (int)((V >> lane) & 1ull);
  const float xo = po[r0 + lane];
  const float so = 1.f / (1.f + __expf(-xo));       // sigmoid(pred_orig), once
  const float* pik = pi + r0 + lane;                // [K,B,T]: + k*KSTR

  if (lane == 0) atomicAdd(&gcv[b], (float)__popcll(V));

#pragma unroll 4
  for (int k = 0; k < KK; ++k) {
    const float xi = pik[(size_t)k * KSTR];
    const float si = 1.f / (1.f + __expf(-xi));
    const float eff = fabsf(so - si);
    const int ab = (int)((Am >> k) & 1ull);
    float sa = ab ? eff : 0.f;
    float sv = vb ? eff : 0.f;
#pragma unroll
    for (int off = 32; off > 0; off >>= 1) {
      sa += __shfl_down(sa, off);
      sv += __shfl_down(sv, off);
    }
    const unsigned long long cab = __ballot(ab != 0);
    if (lane == 0) {
      atomicAdd(&gsa[k * BB + b], sa);
      atomicAdd(&gsv[k * BB + b], sv);
      atomicAdd(&gca[k * BB + b], (float)__popcll(cab));
    }
  }
}

// ---------------------------------------------------------------------------
// Finalize: 1 block, 256 threads over the 2048 (k,b) pairs.
// ---------------------------------------------------------------------------
__global__ __launch_bounds__(256) void fin_kernel(
    const float* __restrict__ gsa, const float* __restrict__ gsv,
    const float* __restrict__ gca, const float* __restrict__ gcv,
    float* __restrict__ out) {
  float s = 0.f;
  for (int i = threadIdx.x; i < KK * BB; i += 256) {
    const int b = i & (BB - 1);
    const float ca = gca[i];
    const float cn = gcv[b] - ca;
    if (ca > 0.f && cn > 0.f) {
      const float sa = gsa[i];
      const float sv = gsv[i];
      const float d = MARGIN_F - (sa / ca - (sv - sa) / cn);
      s += d > 0.f ? d : 0.f;
    }
  }
#pragma unroll
  for (int off = 32; off > 0; off >>= 1) s += __shfl_down(s, off);
  __shared__ float ws4[4];
  if ((threadIdx.x & 63) == 0) ws4[threadIdx.x >> 6] = s;
  __syncthreads();
  if (threadIdx.x == 0) {
    const float S = ws4[0] + ws4[1] + ws4[2] + ws4[3];
    const float ac = S * (1.0f / (float)(KK * BB));
    out[0] = ac;
    out[1] = ac * LAMBDA_F;
  }
}

extern "C" void kernel_launch(void* const* d_in, const int* in_sizes, int n_in,
                              void* d_out, int out_size, void* d_ws, size_t ws_size,
                              hipStream_t stream) {
  const float* pred_orig = (const float*)d_in[0];   // [B,TV] fp32
  const float* pred_int  = (const float*)d_in[1];   // [K,B,TV] fp32
  const int*   idx       = (const int*)d_in[2];     // [K] int32
  const int*   gt        = (const int*)d_in[3];     // [B,TV,TS] int32
  const int*   mv        = (const int*)d_in[4];     // [B,TV] int32
  float* out = (float*)d_out;

  float* gsa = (float*)d_ws;
  float* gsv = gsa + KK * BB;
  float* gca = gsv + KK * BB;
  float* gcv = gca + KK * BB;

  // zero the 24.7 KB accumulator region (ws is re-poisoned each call)
  hipMemsetAsync(d_ws, 0, (size_t)(3 * KK * BB + BB) * sizeof(float), stream);
  fused_kernel<<<(BB * TV) / (64 * 4), 256, 0, stream>>>(
      pred_orig, pred_int, idx, gt, mv, gsa, gsv, gca, gcv);
  fin_kernel<<<1, 256, 0, stream>>>(gsa, gsv, gca, gcv, out);
}

// Round 3
// 292.924 us; speedup vs baseline: 1.3583x; 1.3583x over previous
//
#include <hip/hip_runtime.h>
#include <cstdint>

// Problem constants (from reference)
#define BB 32
#define TV 8192
#define KK 64
#define TS 128
#define MARGIN_F 0.1f
#define LAMBDA_F 0.5f

static constexpr int KSTR = BB * TV;          // pred_intervened stride per k
static constexpr int WPB = TV / 64;           // 128 waves (64-row groups) per batch
static constexpr int NWAVE = BB * WPB;        // 4096 row-groups total

// Workspace layout (bytes):
//   acc   @ 0      : 1 float   (sum of per-pair hinge terms)
//   len   @ 64     : 32 ints   (valid count per b == prefix length)
//   wsV   @ 4096   : u64[4096]     bit r = valid(row r of group)      (32 KB)
//   wsA   @ 65536  : u64[4096][64] [group][k] bit r = aligned&valid   (2 MB)
static constexpr size_t ACC_OFF = 0;
static constexpr size_t LEN_OFF = 64;
static constexpr size_t WSV_OFF = 4096;
static constexpr size_t WSA_OFF = 65536;

// ---------------------------------------------------------------------------
// Pack: each wave owns 64 consecutive rows r = b*TV + t (one "group").
// Coalesced int4 stream of gt_mask (1 KB/wave-load = 2 rows); lane k
// accumulates ITS OWN 64-bit plane (bit r = gt[row r, idx[k]]>0), masked by
// validity at the end. One coalesced 512 B store per wave. Fully-invalid
// groups skip the gt stream entirely (~25% of rows on average).
// Bit-extraction logic identical to the R1/R2 pack that verified absmax 0:
// row0 col c -> ballot bit c>>2 of component c&3; row1 -> bit 32+(c>>2).
// ---------------------------------------------------------------------------
__global__ __launch_bounds__(256) void pack_kernel(
    const int* __restrict__ gt, const int* __restrict__ mv,
    const int* __restrict__ idx,
    unsigned long long* __restrict__ wsA, unsigned long long* __restrict__ wsV,
    int* __restrict__ len) {
  const int lane = threadIdx.x & 63;
  const int wave = blockIdx.x * 4 + (threadIdx.x >> 6);  // group id, 0..4095
  const int r0 = wave * 64;
  const int b = r0 >> 13;                                // TV = 8192
  const int c = idx[lane];                               // lane == k
  const int csel = c & 3, csh = c >> 2;

  const unsigned long long V = __ballot(mv[r0 + lane] != 0);
  if (lane == 0) {
    wsV[wave] = V;
    atomicAdd(&len[b], __popcll(V));
  }

  unsigned long long plane = 0ull;
  if (V != 0ull) {
    const int4* rowp = (const int4*)(gt + (size_t)r0 * TS);
#pragma unroll 4
    for (int ch = 0; ch < 32; ++ch) {
      int4 v = rowp[ch * 64 + lane];                     // 2 rows per wave-load
      unsigned long long b0 = __ballot(v.x > 0);
      unsigned long long b1 = __ballot(v.y > 0);
      unsigned long long b2 = __ballot(v.z > 0);
      unsigned long long b3 = __ballot(v.w > 0);
      unsigned long long sel =
          (csel == 0) ? b0 : (csel == 1) ? b1 : (csel == 2) ? b2 : b3;
      const unsigned long long raw0 = (sel >> csh) & 1ull;         // row 2ch
      const unsigned long long raw1 = (sel >> (32 + csh)) & 1ull;  // row 2ch+1
      plane |= (raw0 << (2 * ch)) | (raw1 << (2 * ch + 1));
    }
    plane &= V;  // aligned requires valid
  }
  wsA[(size_t)wave * 64 + lane] = plane;  // coalesced: 64 lanes x 8 B
}

// ---------------------------------------------------------------------------
// Main: one block per (k,b). Streams pred_intervened with float4 (each elem
// read once from HBM, only up to len[b]); masks come from 2 KB of LDS
// bit-planes. Single block reduction at the end; block computes its own
// per-pair hinge term (cn = len - ca) -> ONE atomicAdd per block.
// ---------------------------------------------------------------------------
__global__ __launch_bounds__(256) void main_kernel(
    const float* __restrict__ po, const float* __restrict__ pi,
    const unsigned long long* __restrict__ wsA,
    const unsigned long long* __restrict__ wsV,
    const int* __restrict__ len, float* __restrict__ acc) {
  const int k = blockIdx.x & (KK - 1);
  const int b = blockIdx.x >> 6;
  const int tid = threadIdx.x;

  __shared__ unsigned long long sA[WPB];  // bit t%64 over groups of this b, my k
  __shared__ unsigned long long sV[WPB];
  if (tid < WPB) sA[tid] = wsA[(size_t)(b * WPB + tid) * 64 + k];
  else           sV[tid - WPB] = wsV[b * WPB + (tid - WPB)];
  __syncthreads();

  const float* pob = po + (size_t)b * TV;
  const float* pik = pi + (size_t)k * KSTR + (size_t)b * TV;
  const int L = len[b];                       // prefix length, >= TV/2
  const int Tlim = (L + 1023) & ~1023;        // iteration granularity 256*4

  float sa = 0.f, sv = 0.f;
  int ca = 0;
  for (int t0 = tid * 4; t0 < Tlim; t0 += 1024) {
    const float4 xo = *(const float4*)(pob + t0);
    const float4 xi = *(const float4*)(pik + t0);
    const int sh = t0 & 63;                   // t0 % 4 == 0 -> sh <= 60
    const unsigned ab = (unsigned)((sA[t0 >> 6] >> sh) & 15ull);
    const unsigned vb = (unsigned)((sV[t0 >> 6] >> sh) & 15ull);
    {
      const float e = fabsf(1.f / (1.f + __expf(-xo.x)) - 1.f / (1.f + __expf(-xi.x)));
      if (ab & 1u) sa += e;
      if (vb & 1u) sv += e;
    }
    {
      const float e = fabsf(1.f / (1.f + __expf(-xo.y)) - 1.f / (1.f + __expf(-xi.y)));
      if (ab & 2u) sa += e;
      if (vb & 2u) sv += e;
    }
    {
      const float e = fabsf(1.f / (1.f + __expf(-xo.z)) - 1.f / (1.f + __expf(-xi.z)));
      if (ab & 4u) sa += e;
      if (vb & 4u) sv += e;
    }
    {
      const float e = fabsf(1.f / (1.f + __expf(-xo.w)) - 1.f / (1.f + __expf(-xi.w)));
      if (ab & 8u) sa += e;
      if (vb & 8u) sv += e;
    }
    ca += __popc(ab);
  }

  // block reduction (once per block)
  float fca = (float)ca;
#pragma unroll
  for (int off = 32; off > 0; off >>= 1) {
    sa += __shfl_down(sa, off);
    sv += __shfl_down(sv, off);
    fca += __shfl_down(fca, off);
  }
  __shared__ float p0[4], p1[4], p2[4];
  const int w = tid >> 6;
  if ((tid & 63) == 0) { p0[w] = sa; p1[w] = sv; p2[w] = fca; }
  __syncthreads();
  if (tid == 0) {
    const float SA = p0[0] + p0[1] + p0[2] + p0[3];
    const float SV = p1[0] + p1[1] + p1[2] + p1[3];
    const float CA = p2[0] + p2[1] + p2[2] + p2[3];
    const float CN = (float)L - CA;           // non-aligned = valid minus aligned
    float pp = 0.f;
    if (CA > 0.f && CN > 0.f) {
      const float d = MARGIN_F - (SA / CA - (SV - SA) / CN);
      pp = d > 0.f ? d : 0.f;
    }
    atomicAdd(acc, pp);
  }
}

__global__ void fin_kernel(const float* __restrict__ acc, float* __restrict__ out) {
  const float ac = acc[0] * (1.0f / (float)(KK * BB));
  out[0] = ac;
  out[1] = ac * LAMBDA_F;
}

extern "C" void kernel_launch(void* const* d_in, const int* in_sizes, int n_in,
                              void* d_out, int out_size, void* d_ws, size_t ws_size,
                              hipStream_t stream) {
  const float* pred_orig = (const float*)d_in[0];   // [B,TV] fp32
  const float* pred_int  = (const float*)d_in[1];   // [K,B,TV] fp32
  const int*   idx       = (const int*)d_in[2];     // [K] int32
  const int*   gt        = (const int*)d_in[3];     // [B,TV,TS] int32
  const int*   mv        = (const int*)d_in[4];     // [B,TV] int32
  float* out = (float*)d_out;

  char* ws = (char*)d_ws;
  float* acc = (float*)(ws + ACC_OFF);
  int* len = (int*)(ws + LEN_OFF);
  unsigned long long* wsV = (unsigned long long*)(ws + WSV_OFF);
  unsigned long long* wsA = (unsigned long long*)(ws + WSA_OFF);

  // zero acc + len (ws is re-poisoned to 0xAA before every call)
  hipMemsetAsync(ws, 0, 192, stream);
  pack_kernel<<<NWAVE / 4, 256, 0, stream>>>(gt, mv, idx, wsA, wsV, len);
  main_kernel<<<BB * KK, 256, 0, stream>>>(pred_orig, pred_int, wsA, wsV, len, acc);
  fin_kernel<<<1, 1, 0, stream>>>(acc, out);
}

// Round 4
// 263.822 us; speedup vs baseline: 1.5081x; 1.1103x over previous
//
#include <hip/hip_runtime.h>
#include <cstdint>

// Problem constants (from reference)
#define BB 32
#define TV 8192
#define KK 64
#define TS 128
#define MARGIN_F 0.1f
#define LAMBDA_F 0.5f

#define TT 256                                 // t-tile per block
static constexpr int KSTR = BB * TV;           // pred_intervened stride per k
static constexpr int NTILE = TV / TT;          // 32 tiles per batch

// Workspace (floats, contiguous so one memset covers):
//   gsa[KK*BB] : sum(eff*aligned) per (k,b)
//   gsv[KK*BB] : sum(eff*valid)   per (k,b)
//   gca[KK*BB] : count(aligned)   per (k,b)  (exact in fp32, <= 8192)
//   len[BB]    : count(valid)     per b      (int)
// en = (gsv-gsa)/(len-gca)  (aligned is a subset of valid).

// ---------------------------------------------------------------------------
// ONE fused kernel. Block = (b, 256-t tile), 256 threads = 4 waves.
// Phase A: wave w packs rows [t0+64w, t0+64w+64): coalesced int4 gt stream +
//          ballot-transpose (bit logic verbatim from R1/R3, absmax 0.0) into
//          LDS planes[w][k]; also sigmoid(pred_orig) tile into LDS (computed
//          ONCE, reused by all 64 k).
// Phase B: wave w owns k in [16w,16w+16). Per k: ONE coalesced float4 pi
//          load per lane, register accumulation, 2 LDS stores to [k][lane].
//          NO shuffles / NO atomics / NO cross-lane in the k-loop (R2's bug).
// Epilogue: block reduces LDS slabs (padded, conflict-free), ~3 coalesced
//          atomic instructions per block. ca from popcll(planes) directly.
// ---------------------------------------------------------------------------
__global__ __launch_bounds__(256, 4) void fused_kernel(
    const float* __restrict__ po, const float* __restrict__ pi,
    const int* __restrict__ idx, const int* __restrict__ gt,
    const int* __restrict__ mv,
    float* __restrict__ gsa, float* __restrict__ gsv,
    float* __restrict__ gca, int* __restrict__ len) {
  const int tid = threadIdx.x;
  const int lane = tid & 63;
  const int w = tid >> 6;
  const int tile = blockIdx.x & (NTILE - 1);
  const int b = blockIdx.x >> 5;               // log2(NTILE)=5
  const int t0 = tile * TT;

  __shared__ unsigned long long planes[4][65]; // [group][k], +1 pad
  __shared__ unsigned long long sVg[4];        // valid bits per group
  __shared__ float so[TT];                     // sigmoid(pred_orig) tile
  __shared__ float saL[KK][65];                // per-(k,lane) partials, padded
  __shared__ float svL[KK][65];

  // ---- Phase A ----
  const int r0 = b * TV + t0 + w * 64;         // global row of this wave's group
  const unsigned long long V = __ballot(mv[r0 + lane] != 0);
  if (lane == 0) {
    sVg[w] = V;
    if (V) atomicAdd(&len[b], __popcll(V));
  }
  so[tid] = __fdividef(1.f, 1.f + __expf(-po[b * TV + t0 + tid]));

  const int c = idx[lane];                     // lane extracts column for k=lane
  const int csel = c & 3, csh = c >> 2;
  unsigned long long plane = 0ull;
  if (V != 0ull) {
    const int4* rowp = (const int4*)(gt + (size_t)r0 * TS);
#pragma unroll 4
    for (int ch = 0; ch < 32; ++ch) {
      int4 v = rowp[ch * 64 + lane];           // 1 KB/wave-load = 2 full rows
      unsigned long long b0 = __ballot(v.x > 0);
      unsigned long long b1 = __ballot(v.y > 0);
      unsigned long long b2 = __ballot(v.z > 0);
      unsigned long long b3 = __ballot(v.w > 0);
      unsigned long long sel =
          (csel == 0) ? b0 : (csel == 1) ? b1 : (csel == 2) ? b2 : b3;
      const unsigned long long raw0 = (sel >> csh) & 1ull;          // row 2ch
      const unsigned long long raw1 = (sel >> (32 + csh)) & 1ull;   // row 2ch+1
      plane |= (raw0 << (2 * ch)) | (raw1 << (2 * ch + 1));
    }
    plane &= V;                                // aligned requires valid
  }
  planes[w][lane] = plane;
  __syncthreads();

  // fully-invalid tile (t0 beyond this batch's valid prefix): nothing to add
  if ((sVg[0] | sVg[1] | sVg[2] | sVg[3]) == 0ull) return;

  // ---- Phase B ----  lane handles t_local = lane*4 .. lane*4+3
  const int g = lane >> 4;                     // (lane*4)>>6
  const int sh4 = (lane & 15) * 4;             // (lane*4)&63
  const unsigned vb4 = (unsigned)((sVg[g] >> sh4) & 15ull);
  const float4 so4 = *(const float4*)&so[lane * 4];
  const float* pib = pi + (size_t)b * TV + t0 + lane * 4;

#pragma unroll 4
  for (int kk = 0; kk < 16; ++kk) {
    const int k = w * 16 + kk;                 // this wave's exclusive k
    const float4 xi = *(const float4*)(pib + (size_t)k * KSTR);
    const unsigned ab4 = (unsigned)((planes[g][k] >> sh4) & 15ull);
    float sa = 0.f, sv = 0.f;
    {
      const float e = fabsf(so4.x - __fdividef(1.f, 1.f + __expf(-xi.x)));
      if (ab4 & 1u) sa += e;
      if (vb4 & 1u) sv += e;
    }
    {
      const float e = fabsf(so4.y - __fdividef(1.f, 1.f + __expf(-xi.y)));
      if (ab4 & 2u) sa += e;
      if (vb4 & 2u) sv += e;
    }
    {
      const float e = fabsf(so4.z - __fdividef(1.f, 1.f + __expf(-xi.z)));
      if (ab4 & 4u) sa += e;
      if (vb4 & 4u) sv += e;
    }
    {
      const float e = fabsf(so4.w - __fdividef(1.f, 1.f + __expf(-xi.w)));
      if (ab4 & 8u) sa += e;
      if (vb4 & 8u) sv += e;
    }
    saL[k][lane] = sa;                         // exclusive (k per wave): no race
    svL[k][lane] = sv;
  }
  __syncthreads();

  // ---- Epilogue: block-level reduce, once ----
  if (tid < KK) {
    const int k = tid;
    float S = 0.f;
    int ca = 0;
#pragma unroll 8
    for (int j = 0; j < 64; ++j) S += saL[k][j];
#pragma unroll
    for (int gg = 0; gg < 4; ++gg) ca += __popcll(planes[gg][k]);
    atomicAdd(&gsa[k * BB + b], S);
    if (ca) atomicAdd(&gca[k * BB + b], (float)ca);
  } else if (tid < 2 * KK) {
    const int k = tid - KK;
    float S = 0.f;
#pragma unroll 8
    for (int j = 0; j < 64; ++j) S += svL[k][j];
    atomicAdd(&gsv[k * BB + b], S);
  }
}

// ---------------------------------------------------------------------------
// Finalize: 1 block over the 2048 (k,b) pairs (logic verified in R2/R3).
// ---------------------------------------------------------------------------
__global__ __launch_bounds__(256) void fin_kernel(
    const float* __restrict__ gsa, const float* __restrict__ gsv,
    const float* __restrict__ gca, const int* __restrict__ len,
    float* __restrict__ out) {
  float s = 0.f;
  for (int i = threadIdx.x; i < KK * BB; i += 256) {
    const int b = i & (BB - 1);
    const float ca = gca[i];
    const float cn = (float)len[b] - ca;
    if (ca > 0.f && cn > 0.f) {
      const float sa = gsa[i];
      const float sv = gsv[i];
      const float d = MARGIN_F - (sa / ca - (sv - sa) / cn);
      s += d > 0.f ? d : 0.f;
    }
  }
#pragma unroll
  for (int off = 32; off > 0; off >>= 1) s += __shfl_down(s, off);
  __shared__ float ws4[4];
  if ((threadIdx.x & 63) == 0) ws4[threadIdx.x >> 6] = s;
  __syncthreads();
  if (threadIdx.x == 0) {
    const float S = ws4[0] + ws4[1] + ws4[2] + ws4[3];
    const float ac = S * (1.0f / (float)(KK * BB));
    out[0] = ac;
    out[1] = ac * LAMBDA_F;
  }
}

extern "C" void kernel_launch(void* const* d_in, const int* in_sizes, int n_in,
                              void* d_out, int out_size, void* d_ws, size_t ws_size,
                              hipStream_t stream) {
  const float* pred_orig = (const float*)d_in[0];   // [B,TV] fp32
  const float* pred_int  = (const float*)d_in[1];   // [K,B,TV] fp32
  const int*   idx       = (const int*)d_in[2];     // [K] int32
  const int*   gt        = (const int*)d_in[3];     // [B,TV,TS] int32
  const int*   mv        = (const int*)d_in[4];     // [B,TV] int32
  float* out = (float*)d_out;

  float* gsa = (float*)d_ws;
  float* gsv = gsa + KK * BB;
  float* gca = gsv + KK * BB;
  int*   len = (int*)(gca + KK * BB);

  // zero the 24.7 KB accumulator region (ws re-poisoned to 0xAA each call)
  hipMemsetAsync(d_ws, 0, (size_t)(3 * KK * BB) * sizeof(float) + BB * sizeof(int),
                 stream);
  fused_kernel<<<BB * NTILE, 256, 0, stream>>>(
      pred_orig, pred_int, idx, gt, mv, gsa, gsv, gca, len);
  fin_kernel<<<1, 256, 0, stream>>>(gsa, gsv, gca, len, out);
}